// Round 5
// baseline (282.594 us; speedup 1.0000x reference)
//
#include <hip/hip_runtime.h>
#include <hip/hip_bf16.h>

#define HH    48
#define WW    64
#define CC    256
#define ND    21
#define OUTD  441

typedef __bf16 v8bf16 __attribute__((ext_vector_type(8)));
typedef float  v4f    __attribute__((ext_vector_type(4)));

// out[b,h,w, tj*21+ti] = (1/256) * sum_c A[b,h,w,c] * Bpad[b, h+2tj-20, w+2ti-20, c]
//
// R0-R4: every LDS-staged lockstep variant pinned at ~90us / 2.3-2.5 TB/s HBM rate
// regardless of occupancy, staging volume, write layout, barrier semantics -- while
// R2's trivial barrier-free permute kernel streamed at ~10 TB/s on the same rig.
// Conclusion: the block-lockstep staging structure itself (bursty barrier-gated
// loads, ~8300 cy/iter exposed latency) is the wall. This version is k2-shaped:
// NO LDS, NO barriers. One wave = (b, h-pair, p, mt, tj-half); B fragments loaded
// straight from global into registers (lane(n,quad) reads 32B contiguous at
// B[hb][2j'+p][kc*32+quad*8] -- identical fragment layout to the old LDS read,
// full-line coalesced per 4-quad group) and cast to bf16 at use. Each staged row
// still serves 2 (h,tj) pairs in-register. B re-reads (~880MB) hit L2/L3; a
// bijective XCD swizzle pins each XCD to 2 images (96 blocks/image) for locality.
__global__ __launch_bounds__(128)
void corr_mfma_kernel(const float* __restrict__ A, const float* __restrict__ B,
                      float* __restrict__ out) {
    // bijective XCD swizzle (m204 form, nwg=1536, 8 XCDs, q=192):
    // XCD x gets wg in [x*192,(x+1)*192) = images {2x, 2x+1}.
    const int bid = blockIdx.x;
    const int wg  = (bid & 7) * 192 + (bid >> 3);
    const int b   = wg / 96;          // 96 blocks/image
    const int r   = wg - b * 96;
    const int ck  = r & 1;            // tj-half (0 = low, 1 = high)
    const int p   = (r >> 1) & 1;     // w parity
    const int hp  = r >> 2;           // [0,24): same-parity h-pair
    const int h0  = (hp & 1) + 4 * (hp >> 1);   // rows h0, h0+2

    const int tid  = threadIdx.x;
    const int lane = tid & 63;
    const int mt   = tid >> 6;        // wave in block = w'-tile
    const int n    = lane & 15;
    const int quad = lane >> 4;

    // shared-row index: hb = h0 - 20 + 2i; row h0 takes tj=i, row h0+2 takes tj=i-1.
    // hb in [0,48) AND tj-window [0,21] => i in [I_lo, I_hi].
    const int I_lo = (h0 >= 20) ? 0 : ((21 - h0) >> 1);
    const int I_hi = min(21, (67 - h0) >> 1);
    const int i_mid = (I_lo + I_hi + 1) >> 1;
    const int i_beg = ck ? i_mid : I_lo;        // contiguous, disjoint halves,
    const int i_end = ck ? I_hi : (i_mid - 1);  // both non-empty (range >= 12)

    // ---- zero-fill invalid-tj strips for this wave's mt w-range ----
    auto zero_tj = [&](int h, int z_lo, int z_hi) {
        if (z_lo > z_hi) return;
        float* outr = out + (size_t)(b * HH + h) * WW * OUTD;
        for (int tj = z_lo; tj <= z_hi; ++tj)
            for (int idx = lane; idx < 16 * ND; idx += 64) {
                int wl = idx / ND, ti = idx - wl * ND;
                int w  = ((mt * 16 + wl) << 1) + p;
                outr[(size_t)w * OUTD + tj * ND + ti] = 0.f;
            }
    };
    // row h0 computed tj = [I_lo, min(20,I_hi)]; row h0+2 = [max(0,I_lo-1), min(20,I_hi-1)]
    if (ck == 0) {
        zero_tj(h0,     0, I_lo - 1);
        zero_tj(h0 + 2, 0, max(0, I_lo - 1) - 1);
    } else {
        zero_tj(h0,     min(20, I_hi) + 1,     20);
        zero_tj(h0 + 2, min(20, I_hi - 1) + 1, 20);
    }

    // ---- A fragments: two h-rows (loop-invariant, loaded once) ----
    v8bf16 afrag[2][8];
    {
        int w_a = ((mt * 16 + n) << 1) + p;
        #pragma unroll
        for (int rr = 0; rr < 2; ++rr) {
            const float* arow = A + ((size_t)(b * HH + h0 + 2 * rr) * WW + w_a) * CC;
            #pragma unroll
            for (int kc = 0; kc < 8; ++kc) {
                int c0 = kc * 32 + quad * 8;
                float4 f0 = *(const float4*)(arow + c0);
                float4 f1 = *(const float4*)(arow + c0 + 4);
                v8bf16 af;
                af[0] = (__bf16)f0.x; af[1] = (__bf16)f0.y; af[2] = (__bf16)f0.z; af[3] = (__bf16)f0.w;
                af[4] = (__bf16)f1.x; af[5] = (__bf16)f1.y; af[6] = (__bf16)f1.z; af[7] = (__bf16)f1.w;
                afrag[rr][kc] = af;
            }
        }
    }

    // epilogue: D col = n (-> j'), row = quad*4 + q (-> w' within tile)
    auto epilogue = [&](const v4f& acc0, const v4f& acc1, int h, int tj) {
        float* outr = out + (size_t)(b * HH + h) * WW * OUTD;
        #pragma unroll
        for (int q = 0; q < 4; ++q) {
            int wp = mt * 16 + quad * 4 + q;
            int w  = (wp << 1) + p;
            float* orow = outr + (size_t)w * OUTD + tj * ND;
            int ti0 = 10 + n - wp;
            if ((unsigned)ti0 < 21u) orow[ti0] = acc0[q] * (1.f / 256.f);
            int ti1 = 26 + n - wp;
            if ((unsigned)ti1 < 21u) orow[ti1] = acc1[q] * (1.f / 256.f);
            // out-of-image j => exact zeros
            if (n < 10 - wp)  orow[n]      = 0.f;
            if (n <= wp - 22) orow[20 - n] = 0.f;
        }
    };

    const float* bimg = B + (size_t)(b * HH) * WW * CC;

    for (int i = i_beg; i <= i_end; ++i) {
        const int hb = h0 - 20 + 2 * i;
        // B fragments straight from global: lane(n,quad) reads rows j'=n and 16+n,
        // 32B contiguous each; 4 quads cover a full 128B line per row. No staging.
        const float* brow = bimg + ((size_t)hb * WW + p) * CC;
        const float* bl = brow + (size_t)(2 * n) * CC + quad * 8;
        const float* bh = brow + (size_t)(2 * (16 + n)) * CC + quad * 8;

        v4f a00 = {0.f, 0.f, 0.f, 0.f};
        v4f a01 = a00, a10 = a00, a11 = a00;
        #pragma unroll
        for (int kc = 0; kc < 8; ++kc) {
            float4 f0 = *(const float4*)(bl + kc * 32);
            float4 f1 = *(const float4*)(bl + kc * 32 + 4);
            float4 g0 = *(const float4*)(bh + kc * 32);
            float4 g1 = *(const float4*)(bh + kc * 32 + 4);
            v8bf16 bf0, bf1;
            bf0[0] = (__bf16)f0.x; bf0[1] = (__bf16)f0.y; bf0[2] = (__bf16)f0.z; bf0[3] = (__bf16)f0.w;
            bf0[4] = (__bf16)f1.x; bf0[5] = (__bf16)f1.y; bf0[6] = (__bf16)f1.z; bf0[7] = (__bf16)f1.w;
            bf1[0] = (__bf16)g0.x; bf1[1] = (__bf16)g0.y; bf1[2] = (__bf16)g0.z; bf1[3] = (__bf16)g0.w;
            bf1[4] = (__bf16)g1.x; bf1[5] = (__bf16)g1.y; bf1[6] = (__bf16)g1.z; bf1[7] = (__bf16)g1.w;
            a00 = __builtin_amdgcn_mfma_f32_16x16x32_bf16(afrag[0][kc], bf0, a00, 0, 0, 0);
            a01 = __builtin_amdgcn_mfma_f32_16x16x32_bf16(afrag[0][kc], bf1, a01, 0, 0, 0);
            a10 = __builtin_amdgcn_mfma_f32_16x16x32_bf16(afrag[1][kc], bf0, a10, 0, 0, 0);
            a11 = __builtin_amdgcn_mfma_f32_16x16x32_bf16(afrag[1][kc], bf1, a11, 0, 0, 0);
        }
        if (i <= 20) epilogue(a00, a01, h0,     i);       // row h0,   tj = i
        if (i >= 1)  epilogue(a10, a11, h0 + 2, i - 1);   // row h0+2, tj = i-1
    }
}

extern "C" void kernel_launch(void* const* d_in, const int* in_sizes, int n_in,
                              void* d_out, int out_size, void* d_ws, size_t ws_size,
                              hipStream_t stream) {
    const float* A = (const float*)d_in[0];
    const float* B = (const float*)d_in[1];
    float* out = (float*)d_out;
    dim3 grid(1536);
    dim3 block(128);
    corr_mfma_kernel<<<grid, block, 0, stream>>>(A, B, out);
}

// Round 6
// 268.302 us; speedup vs baseline: 1.0533x; 1.0533x over previous
//
#include <hip/hip_runtime.h>
#include <hip/hip_bf16.h>

#define HH    48
#define WW    64
#define CC    256
#define ND    21
#define OUTD  441
#define PITCH 264               // LDS row pitch in bf16 elems
#define PLANE (32 * PITCH)      // one parity plane: 32 j'-rows
#define TJH   11                // max owned tj per block (ck0: 11, ck1: 10)

typedef __bf16 v8bf16 __attribute__((ext_vector_type(8)));
typedef __bf16 v4bf16 __attribute__((ext_vector_type(4)));
typedef float  v4f    __attribute__((ext_vector_type(4)));

// out[b,h,w, tj*21+ti] = (1/256) * sum_c A[b,h,w,c] * Bpad[b, h+2tj-20, w+2ti-20, c]
//
// R0-R5 lesson: dur tracks HBM bytes at a fixed ~2.4 TB/s for the scattered-store
// variants (writes 1.94x amplified by 84B partial-sector strips); streaming kernels
// on the same rig run ~3x faster. This version is the minimum-byte single-pass:
// block = (b, h, tj-half). Per-tj MFMA results stay in REGISTERS (acc[11], static
// indexing), B rows staged in LDS (single buffer + reg prefetch, proven R2 pattern),
// and the epilogue repacks through LDS to write out rows as dense consecutive
// dwords -- out written exactly once, full-line. Invalid tj (|hb| out of image) and
// out-of-image ti are zeros by construction (acc/LDS zero-init): no zero-fill pass.
__global__ __launch_bounds__(512, 2)
void corr_mfma_kernel(const float* __restrict__ A, const float* __restrict__ B,
                      float* __restrict__ out) {
    __shared__ __bf16 Bst[2 * PLANE];   // 33,792 B staging; repack reuses first 14.8 KB

    // XCD-chunked bijective swizzle (1536 = 8 * 192): 2 images per XCD.
    const int bid = blockIdx.x;
    const int wg  = (bid & 7) * 192 + (bid >> 3);
    const int b   = wg / 96;          // image
    const int rem = wg - b * 96;
    const int h   = rem >> 1;         // output row
    const int ck  = rem & 1;          // tj-half: ck0 owns [0,10], ck1 owns [11,20]

    const int tid  = threadIdx.x;
    const int lane = tid & 63;
    const int wave = tid >> 6;        // 8 waves = (p, mt, nc)
    const int p    = wave & 1;        // w parity
    const int mt   = (wave >> 1) & 1; // w'-tile
    const int nc   = wave >> 2;       // j''-chain
    const int n    = lane & 15;
    const int quad = lane >> 4;

    // valid tj range: hb = h + 2tj - 20 in [0,48)
    const int tj_lo = (h >= 21) ? 0 : ((21 - h) >> 1);
    const int tj_hi = min(20, (67 - h) >> 1);
    const int own0  = ck ? 11 : 0;
    const int n_own = ck ? 10 : 11;
    const int c_lo  = max(own0, tj_lo);
    const int c_hi  = min(own0 + n_own - 1, tj_hi);   // may be < c_lo (empty; h>=46 ck1)

    // ---- A fragments (loop-invariant, loaded once; proven layout) ----
    v8bf16 afrag[8];
    {
        int w_a = ((mt * 16 + n) << 1) + p;
        const float* arow = A + ((size_t)(b * HH + h) * WW + w_a) * CC;
        #pragma unroll
        for (int kc = 0; kc < 8; ++kc) {
            int c0 = kc * 32 + quad * 8;
            float4 f0 = *(const float4*)(arow + c0);
            float4 f1 = *(const float4*)(arow + c0 + 4);
            v8bf16 af;
            af[0] = (__bf16)f0.x; af[1] = (__bf16)f0.y; af[2] = (__bf16)f0.z; af[3] = (__bf16)f0.w;
            af[4] = (__bf16)f1.x; af[5] = (__bf16)f1.y; af[6] = (__bf16)f1.z; af[7] = (__bf16)f1.w;
            afrag[kc] = af;
        }
    }

    // ---- staging: full B row (both parities), 4096 float4-chunks over 512 thr ----
    const float* bimg = B + (size_t)(b * HH) * WW * CC;
    float4 pf[8];
    auto load_pf = [&](int hb) {
        const float* brow = bimg + (size_t)hb * WW * CC;
        #pragma unroll
        for (int it = 0; it < 8; ++it)
            pf[it] = *(const float4*)(brow + 4 * (it * 512 + tid));
    };
    auto store_lds = [&]() {
        #pragma unroll
        for (int it = 0; it < 8; ++it) {
            int m  = it * 512 + tid;
            int j  = m >> 6;            // B col (0..63)
            int c4 = m & 63;            // float4 within row
            v4bf16 t;
            t[0] = (__bf16)pf[it].x; t[1] = (__bf16)pf[it].y;
            t[2] = (__bf16)pf[it].z; t[3] = (__bf16)pf[it].w;
            *(v4bf16*)&Bst[(j & 1) * PLANE + (j >> 1) * PITCH + c4 * 4] = t;
        }
    };

    v4f acc[TJH];
    #pragma unroll
    for (int s = 0; s < TJH; ++s) acc[s] = (v4f){0.f, 0.f, 0.f, 0.f};

    if (c_lo <= c_hi) { load_pf(h + 2 * c_lo - 20); store_lds(); }

    const __bf16* bb = Bst + p * PLANE + (nc * 16 + n) * PITCH + quad * 8;

    // Main loop: fully unrolled over owned slots so acc[] stays in registers
    // (rule #20: static indexing). All guards are block-uniform -> barrier-safe.
    #pragma unroll
    for (int s = 0; s < TJH; ++s) {
        const int tj = own0 + s;
        if (tj >= c_lo && tj <= c_hi) {
            __syncthreads();                              // staged row visible
            if (tj < c_hi) load_pf(h + 2 * (tj + 1) - 20); // prefetch next (in flight)
            #pragma unroll
            for (int kc = 0; kc < 8; ++kc) {
                v8bf16 bf = *(const v8bf16*)(bb + kc * 32);
                acc[s] = __builtin_amdgcn_mfma_f32_16x16x32_bf16(afrag[kc], bf, acc[s], 0, 0, 0);
            }
            __syncthreads();                              // all reads done
            if (tj < c_hi) store_lds();                   // overwrite buffer
        }
    }

    // ---- repack through LDS + dense coalesced writeout ----
    // 4 chunks of 16 w. Chunk g: w = g*16 + lw, lw = ((quad&1)*4+q)*2 + p,
    // written by waves with mt==g>>1 and lanes with quad>>1==g&1.
    __syncthreads();
    float* ldsf = (float*)Bst;                  // 16 * TJH * 21 = 3696 floats
    const int nfl = n_own * ND;                 // floats per w-row (231 / 210)
    for (int g = 0; g < 4; ++g) {
        for (int idx = tid; idx < 16 * TJH * ND; idx += 512) ldsf[idx] = 0.f;
        __syncthreads();
        if (mt == (g >> 1) && (quad >> 1) == (g & 1)) {
            #pragma unroll
            for (int s = 0; s < TJH; ++s) {
                if (s < n_own) {
                    #pragma unroll
                    for (int q = 0; q < 4; ++q) {
                        int wp = mt * 16 + quad * 4 + q;      // global w'
                        int ti = nc * 16 + n - wp + 10;       // j'' -> ti
                        if ((unsigned)ti < 21u) {
                            int lw = (((quad & 1) * 4 + q) << 1) + p;
                            ldsf[(lw * TJH + s) * ND + ti] = acc[s][q] * (1.f / 256.f);
                        }
                    }
                }
            }
        }
        __syncthreads();
        // stream: 16 w-rows x nfl consecutive floats each -> full-line writes
        float* obase = out + ((size_t)((b * HH + h) * WW) + g * 16) * OUTD + own0 * ND;
        for (int idx = tid; idx < 16 * nfl; idx += 512) {
            int lw = idx / nfl, r = idx - lw * nfl;
            obase[(size_t)lw * OUTD + r] = ldsf[lw * (TJH * ND) + r];
        }
        __syncthreads();
    }
}

extern "C" void kernel_launch(void* const* d_in, const int* in_sizes, int n_in,
                              void* d_out, int out_size, void* d_ws, size_t ws_size,
                              hipStream_t stream) {
    const float* A = (const float*)d_in[0];
    const float* B = (const float*)d_in[1];
    float* out = (float*)d_out;
    dim3 grid(16 * HH * 2);     // (b, h, ck) = 1536 blocks
    dim3 block(512);
    corr_mfma_kernel<<<grid, block, 0, stream>>>(A, B, out);
}

// Round 7
// 202.074 us; speedup vs baseline: 1.3985x; 1.3277x over previous
//
#include <hip/hip_runtime.h>
#include <hip/hip_bf16.h>

#define HH    48
#define WW    64
#define CC    256
#define ND    21
#define OUTD  441
#define PITCH 264        // LDS row pitch in bf16 elems (16B-aligned rows, 4-bank rotate)
#define SROWS 32         // j' rows per parity

typedef __bf16 v8bf16 __attribute__((ext_vector_type(8)));
typedef __bf16 v4bf16 __attribute__((ext_vector_type(4)));
typedef float  v4f    __attribute__((ext_vector_type(4)));

// out[b,h,w, tj*21+ti] = (1/256) * sum_c A[b,h,w,c] * Bpad[b, h+2tj-20, w+2ti-20, c]
//
// R0-R5 invariant: ~15K stall cycles per barrier-delimited iteration, insensitive
// to occupancy/staging-volume/write-layout/barrier-semantics/byte-count. Remaining
// suspect: per-lane-SCATTERED epilogue stores (64 lanes -> 64 strips 3.5KB apart
// => ~60 sector transactions per store inst, ~4000 sector-ops per block-iter,
// ~1/cyc at the TCP/L2 write path == the stall). This version keeps the R3 kernel
// verbatim EXCEPT the epilogue: each wave repacks its 672 output dwords through a
// private LDS scratch (no extra barriers), then stores strip-major consecutive
// dwords (~8 sectors/inst, ~90 sector-ops/wave-iter, 7x fewer).
__global__ __launch_bounds__(384)
void corr_mfma_kernel(const float* __restrict__ A, const float* __restrict__ B,
                      float* __restrict__ out) {
    __shared__ __bf16 Blds[2][SROWS * PITCH];   // 2 x 16,896 B staging
    __shared__ float  Scr[6][2 * 16 * ND];      // per-wave scratch: 672 f = 2,688 B

    const int blk  = blockIdx.x;
    const int b    = blk >> 5;        // 16 images, 32 blocks/image
    const int rem  = blk & 31;
    const int ck   = rem & 1;         // i-range chunk (0 = low half, 1 = high half)
    const int p    = (rem >> 1) & 1;  // w parity
    const int hpar = (rem >> 2) & 1;  // h parity
    const int grp  = rem >> 3;        // [0,4): group of 6 same-parity rows
    const int h0   = hpar + 12 * grp; // block rows: h0 + 2r, r in [0,6)

    const int tid  = threadIdx.x;
    const int lane = tid & 63;
    const int wave = tid >> 6;        // [0,6)
    const int mt   = wave & 1;        // w'-tile
    const int hg   = wave >> 1;       // [0,3): h-pair; wave rows r = 2hg, 2hg+1
    const int n    = lane & 15;
    const int quad = lane >> 4;

    // staged rows: hb = h0 - 20 + 2i, i in [i_lo_f, i_hi_f]
    // row r (h = h0+2r) consumes staged row i = tj + r.
    const int i_lo_f = (h0 >= 20) ? 0 : ((21 - h0) >> 1);
    const int i_hi_f = min(25, (67 - h0) >> 1);
    const int i_mid  = (i_lo_f + i_hi_f + 1) >> 1;
    const int i_lo   = ck ? i_mid : i_lo_f;          // contiguous, disjoint,
    const int i_hi   = ck ? i_hi_f : (i_mid - 1);    // both non-empty (>=7)

    // ---- staging helpers: 32 j'-rows x 64 float4-chunks = 2048 over 384 thr ----
    const float* bimg = B + (size_t)(b * HH) * WW * CC + p * CC;  // +p: j = 2j'+p
    float4 pf[6];
    auto load_pf = [&](int hb) {
        const float* brow = bimg + (size_t)hb * WW * CC;
        #pragma unroll
        for (int it = 0; it < 6; ++it) {
            int idx = it * 384 + tid;
            if (idx < 2048)
                pf[it] = *(const float4*)(brow + (idx >> 6) * 2 * CC + ((idx & 63) << 2));
        }
    };
    auto store_lds = [&](int buf) {
        #pragma unroll
        for (int it = 0; it < 6; ++it) {
            int idx = it * 384 + tid;
            if (idx < 2048) {
                v4bf16 t;
                t[0] = (__bf16)pf[it].x; t[1] = (__bf16)pf[it].y;
                t[2] = (__bf16)pf[it].z; t[3] = (__bf16)pf[it].w;
                *(v4bf16*)&Blds[buf][(idx >> 6) * PITCH + ((idx & 63) << 2)] = t;
            }
        }
    };

    load_pf(h0 - 20 + 2 * i_lo);   // issue early; completes under zero-fill/A-loads

    // ---- one-time scratch zeroing (per-wave region; statically-uncovered slots
    // stay 0 forever and provide the out-of-image-j zeros on every iteration) ----
    #pragma unroll
    for (int k = 0; k < 11; ++k) {
        int idx = k * 64 + lane;
        if (idx < 672) Scr[wave][idx] = 0.f;
    }

    // ---- zero-fill invalid-tj entries for the 6 rows (parity-p w cols only) ----
    // ck0 owns invalid-low tj [0, i_lo_f-r-1]; ck1 invalid-high [i_hi_f-r+1, 20].
    // idx-consecutive => ti-consecutive within strips: already sector-coalesced.
    for (int r = 0; r < 6; ++r) {
        int z_lo, z_hi;
        if (ck == 0) { z_lo = 0;                      z_hi = min(20, i_lo_f - r - 1); }
        else         { z_lo = max(0, i_hi_f - r + 1); z_hi = 20; }
        if (z_lo > z_hi) continue;
        float* outr = out + (size_t)(b * HH + h0 + 2 * r) * WW * OUTD;
        for (int tj = z_lo; tj <= z_hi; ++tj) {
            for (int idx = tid; idx < 32 * ND; idx += 384) {
                int wp = idx / ND, ti = idx - wp * ND;
                int w  = (wp << 1) + p;
                outr[(size_t)w * OUTD + tj * ND + ti] = 0.f;
            }
        }
    }

    // ---- A fragments: two h-rows per wave (loop-invariant, loaded once) ----
    v8bf16 afrag[2][8];
    {
        int w_a = ((mt * 16 + n) << 1) + p;
        #pragma unroll
        for (int rr = 0; rr < 2; ++rr) {
            int h = h0 + 4 * hg + 2 * rr;
            const float* arow = A + ((size_t)(b * HH + h) * WW + w_a) * CC;
            #pragma unroll
            for (int kc = 0; kc < 8; ++kc) {
                int c0 = kc * 32 + quad * 8;
                float4 f0 = *(const float4*)(arow + c0);
                float4 f1 = *(const float4*)(arow + c0 + 4);
                v8bf16 af;
                af[0] = (__bf16)f0.x; af[1] = (__bf16)f0.y; af[2] = (__bf16)f0.z; af[3] = (__bf16)f0.w;
                af[4] = (__bf16)f1.x; af[5] = (__bf16)f1.y; af[6] = (__bf16)f1.z; af[7] = (__bf16)f1.w;
                afrag[rr][kc] = af;
            }
        }
    }

    store_lds(0);
    int cur = 0;

    for (int i = i_lo; i <= i_hi; ++i) {
        if (i < i_hi) load_pf(h0 - 20 + 2 * (i + 1));   // prefetch next hb; stays
                                                        // IN FLIGHT across barrier
        // Raw barrier, writer-side LDS drain only (no vmcnt(0) drain) -- R3-proven.
        asm volatile("s_waitcnt lgkmcnt(0)" ::: "memory");
        __builtin_amdgcn_s_barrier();
        __builtin_amdgcn_sched_barrier(0);

        const int tj0 = i - 2 * hg;        // rr=0 row; rr=1 row has tj0-1
        if ((unsigned)tj0 <= 21u) {        // at least one of the pair valid
            const __bf16* bbase = &Blds[cur][n * PITCH + quad * 8];
            v4f a00 = {0.f, 0.f, 0.f, 0.f};
            v4f a01 = a00, a10 = a00, a11 = a00;
            #pragma unroll
            for (int kc = 0; kc < 8; ++kc) {
                v8bf16 bf0 = *(const v8bf16*)(bbase + kc * 32);                // j' = n
                v8bf16 bf1 = *(const v8bf16*)(bbase + 16 * PITCH + kc * 32);   // j' = 16+n
                a00 = __builtin_amdgcn_mfma_f32_16x16x32_bf16(afrag[0][kc], bf0, a00, 0, 0, 0);
                a01 = __builtin_amdgcn_mfma_f32_16x16x32_bf16(afrag[0][kc], bf1, a01, 0, 0, 0);
                a10 = __builtin_amdgcn_mfma_f32_16x16x32_bf16(afrag[1][kc], bf0, a10, 0, 0, 0);
                a11 = __builtin_amdgcn_mfma_f32_16x16x32_bf16(afrag[1][kc], bf1, a11, 0, 0, 0);
            }

            // ---- repack epilogue: scatter acc -> private LDS scratch ----
            // scratch layout: [r][s][ti], flat = r*336 + s*21 + ti.
            // Banks: addr = 80*quad + 20*q + n + const => 2-way (free).
            #pragma unroll
            for (int q = 0; q < 4; ++q) {
                int s  = quad * 4 + q;
                int wp = mt * 16 + s;
                float* sr = &Scr[wave][s * ND];
                int ti0 = 10 + n - wp;
                if ((unsigned)ti0 < 21u) {
                    sr[ti0]       = a00[q] * (1.f / 256.f);
                    sr[336 + ti0] = a10[q] * (1.f / 256.f);
                }
                int ti1 = 26 + n - wp;
                if ((unsigned)ti1 < 21u) {
                    sr[ti1]       = a01[q] * (1.f / 256.f);
                    sr[336 + ti1] = a11[q] * (1.f / 256.f);
                }
            }
            asm volatile("s_waitcnt lgkmcnt(0)" ::: "memory");

            // ---- gather strip-major + coalesced stores (~8 sectors/inst) ----
            const int ha = h0 + 4 * hg;
            const size_t base0 = (size_t)(b * HH + ha)     * WW * OUTD;
            const size_t base1 = (size_t)(b * HH + ha + 2) * WW * OUTD;
            #pragma unroll
            for (int it = 0; it < 11; ++it) {
                int idx = it * 64 + lane;
                if (idx < 672) {
                    int r   = idx >= 336;
                    int rm  = idx - r * 336;
                    int s   = rm / ND, ti = rm - s * ND;
                    int tjr = tj0 - r;
                    if ((unsigned)tjr <= 20u) {
                        float v = Scr[wave][idx];
                        size_t base = r ? base1 : base0;
                        int w = ((mt * 16 + s) << 1) + p;
                        out[base + (size_t)w * OUTD + tjr * ND + ti] = v;
                    }
                }
            }
        }

        if (i < i_hi) store_lds(cur ^ 1);   // consumes pf -> compiler-counted
                                            // vmcnt(N) lands exactly here (T4)
        cur ^= 1;
    }
}

extern "C" void kernel_launch(void* const* d_in, const int* in_sizes, int n_in,
                              void* d_out, int out_size, void* d_ws, size_t ws_size,
                              hipStream_t stream) {
    const float* A = (const float*)d_in[0];
    const float* B = (const float*)d_in[1];
    float* out = (float*)d_out;
    dim3 grid(16 * 32);
    dim3 block(384);
    corr_mfma_kernel<<<grid, block, 0, stream>>>(A, B, out);
}

// Round 8
// 193.582 us; speedup vs baseline: 1.4598x; 1.0439x over previous
//
#include <hip/hip_runtime.h>
#include <hip/hip_bf16.h>

#define HH    48
#define WW    64
#define CC    256
#define ND    21
#define OUTD  441
#define PITCH 264        // LDS plane row pitch in bf16 elems (proven R2 shape)

typedef __bf16 v8bf16 __attribute__((ext_vector_type(8)));
typedef __bf16 v4bf16 __attribute__((ext_vector_type(4)));
typedef float  v4f    __attribute__((ext_vector_type(4)));

// out[b,h,w, tj*21+ti] = (1/256) * sum_c A[b,h,w,c] * Bpad[b, h+2tj-20, w+2ti-20, c]
//
// R0-R6: every variant with global stores INSIDE the barrier loop lands at 83-95us
// with 1.94x write amplification (strips drain as partial sectors) and all pipes
// idle. This version holds the ENTIRE per-row-half output in registers: block =
// (b, h, p); acc[21] v4f (static indexing via fully-unrolled s-loop, uniform
// guards). Loop does ONLY staging + MFMA (double-buffered LDS, one raw barrier
// per iter, all 4 waves active). Epilogue (once): repack acc through LDS, stream
// 1764B-contiguous per-w strips -> write-amp ~1.0, out written exactly once.
__global__ __launch_bounds__(256, 3)
void corr_mfma_kernel(const float* __restrict__ A, const float* __restrict__ B,
                      float* __restrict__ out) {
    __shared__ __bf16 Blds[2][32 * PITCH];   // 2 x 16,896 B; epilogue reuses as float

    // XCD-chunked bijective swizzle (1536 = 8 * 192): 2 images per XCD; (b,h,0)
    // and (b,h,1) adjacent -> same XCD -> parity-boundary sectors merge in L2.
    const int bid = blockIdx.x;
    const int wg  = (bid & 7) * 192 + (bid >> 3);
    const int b   = wg / 96;          // image
    const int rem = wg - b * 96;
    const int h   = rem >> 1;         // output row
    const int p   = rem & 1;          // w parity

    const int tid  = threadIdx.x;
    const int lane = tid & 63;
    const int wave = tid >> 6;        // 4 waves = (mt, nc)
    const int mt   = wave & 1;        // w'-tile
    const int nc   = wave >> 1;       // j''-tile
    const int n    = lane & 15;
    const int quad = lane >> 4;

    // valid tj: hb = h + 2s - 20 in [0,48) -> s in [s_lo, s_hi] (contiguous, >=11)
    const int s_lo = (h >= 20) ? 0 : ((21 - h) >> 1);
    const int s_hi = min(20, (67 - h) >> 1);

    // ---- staging: one parity plane (32 cols x 256 ch), 2048 float4 / 256 thr ----
    const float* bimg = B + ((size_t)(b * HH) * WW + p) * CC;
    float4 pf[8];
    auto load_pf = [&](int hb) {
        const float* brow = bimg + (size_t)hb * WW * CC;
        #pragma unroll
        for (int it = 0; it < 8; ++it) {
            int idx = it * 256 + tid;
            pf[it] = *(const float4*)(brow + (idx >> 6) * 2 * CC + ((idx & 63) << 2));
        }
    };
    auto store_lds = [&](int buf) {
        #pragma unroll
        for (int it = 0; it < 8; ++it) {
            int idx = it * 256 + tid;
            v4bf16 t;
            t[0] = (__bf16)pf[it].x; t[1] = (__bf16)pf[it].y;
            t[2] = (__bf16)pf[it].z; t[3] = (__bf16)pf[it].w;
            *(v4bf16*)&Blds[buf][(idx >> 6) * PITCH + ((idx & 63) << 2)] = t;
        }
    };

    load_pf(h + 2 * s_lo - 20);    // prologue stage (in flight under A-loads)

    // ---- A fragments (loop-invariant; proven layout; nc-redundant but cheap) ----
    v8bf16 afrag[8];
    {
        int w_a = ((mt * 16 + n) << 1) + p;
        const float* arow = A + ((size_t)(b * HH + h) * WW + w_a) * CC;
        #pragma unroll
        for (int kc = 0; kc < 8; ++kc) {
            int c0 = kc * 32 + quad * 8;
            float4 f0 = *(const float4*)(arow + c0);
            float4 f1 = *(const float4*)(arow + c0 + 4);
            v8bf16 af;
            af[0] = (__bf16)f0.x; af[1] = (__bf16)f0.y; af[2] = (__bf16)f0.z; af[3] = (__bf16)f0.w;
            af[4] = (__bf16)f1.x; af[5] = (__bf16)f1.y; af[6] = (__bf16)f1.z; af[7] = (__bf16)f1.w;
            afrag[kc] = af;
        }
    }

    v4f acc[ND];
    #pragma unroll
    for (int s = 0; s < ND; ++s) acc[s] = (v4f){0.f, 0.f, 0.f, 0.f};

    store_lds(0);
    int cur = 0;

    // ---- main loop: fully unrolled (static acc index), uniform guards ----
    #pragma unroll
    for (int s = 0; s < ND; ++s) {
        if (s >= s_lo && s <= s_hi) {
            if (s < s_hi) load_pf(h + 2 * (s + 1) - 20);   // prefetch next (in flight
                                                           // across the barrier, T4)
            asm volatile("s_waitcnt lgkmcnt(0)" ::: "memory");  // writer-side drain
            __builtin_amdgcn_s_barrier();
            __builtin_amdgcn_sched_barrier(0);

            const __bf16* bb = &Blds[cur][(nc * 16 + n) * PITCH + quad * 8];
            #pragma unroll
            for (int kc = 0; kc < 8; ++kc) {
                v8bf16 bf = *(const v8bf16*)(bb + kc * 32);
                acc[s] = __builtin_amdgcn_mfma_f32_16x16x32_bf16(afrag[kc], bf, acc[s], 0, 0, 0);
            }
            // store to the OTHER buffer: iter s reads cur, iter s+1 reads cur^1;
            // overwrite of cur happens at s+1 AFTER s+1's barrier -> one barrier/iter.
            if (s < s_hi) store_lds(cur ^ 1);
            cur ^= 1;
        }
    }

    // ---- epilogue: repack acc -> LDS -> dense per-w strips (once per block) ----
    // 2 chunks g (= mt tile) of 16 w' each: 16 x 441 floats = 28,224 B in LDS.
    __syncthreads();                      // staging reads done; LDS reusable
    float* ldsf = (float*)Blds;
    for (int g = 0; g < 2; ++g) {
        for (int idx = tid; idx < 16 * OUTD; idx += 256) ldsf[idx] = 0.f;
        __syncthreads();
        if (mt == g) {
            #pragma unroll
            for (int s = 0; s < ND; ++s) {
                #pragma unroll
                for (int q = 0; q < 4; ++q) {
                    int lw = quad * 4 + q;                 // w' within chunk
                    int wp = g * 16 + lw;                  // global parity-w index
                    int ti = nc * 16 + n - wp + 10;        // j'' -> ti
                    if ((unsigned)ti < 21u)                // uncovered ti = out-of-image j = 0
                        ldsf[lw * OUTD + s * ND + ti] = acc[s][q] * (1.f / 256.f);
                }
            }
        }
        __syncthreads();
        // stream: 16 strips of 441 consecutive floats (1764 B contiguous each)
        const size_t obase = (size_t)((b * HH + h) * WW) * OUTD;
        for (int idx = tid; idx < 16 * OUTD; idx += 256) {
            int lw = idx / OUTD, d = idx - lw * OUTD;
            int w  = ((g * 16 + lw) << 1) + p;
            out[obase + (size_t)w * OUTD + d] = ldsf[idx];
        }
        __syncthreads();
    }
}

extern "C" void kernel_launch(void* const* d_in, const int* in_sizes, int n_in,
                              void* d_out, int out_size, void* d_ws, size_t ws_size,
                              hipStream_t stream) {
    const float* A = (const float*)d_in[0];
    const float* B = (const float*)d_in[1];
    float* out = (float*)d_out;
    dim3 grid(16 * HH * 2);     // (b, h, p) = 1536 blocks
    dim3 block(256);
    corr_mfma_kernel<<<grid, block, 0, stream>>>(A, B, out);
}